// Round 10
// baseline (98.562 us; speedup 1.0000x reference)
//
#include <hip/hip_runtime.h>
#include <math.h>

#define DIM 256
#define NUM_EMB 1024
#define ROWS 16384
#define NUMEL 4194304.0f // 8*2048*256

typedef __attribute__((ext_vector_type(8))) short bf16x8;
typedef __attribute__((ext_vector_type(4))) float f32x4;

// f32 -> bf16 round-to-nearest-even (bit pattern)
__device__ __forceinline__ unsigned short f2bf(float f) {
    unsigned int u = __float_as_uint(f);
    u = (u + 0x7FFFu + ((u >> 16) & 1u)) >> 16;
    return (unsigned short)u;
}

// ws layout (bytes):
//   Ebf : [0,      524288)  bf16 codebook, fragment-linear:
//         subtile t=row/16, kc=dim/32 -> 1024B block; lane l=16g+r holds
//         row t*16+r, dims [kc*32+8g,+8) at ushort off (t*8+kc)*512 + l*8
//   esq : [524288, 528384)  f32 [1024] exact codebook row norms
//   bsum: [528384, 529408)  f32 [256]  per-block loss partials

// ---- kprepE: codebook f32 -> fragment-linear bf16 + exact sq-norms ----
__global__ __launch_bounds__(256) void kprepE(
        const float* __restrict__ src, unsigned short* __restrict__ dst,
        float* __restrict__ sq) {
    int t = blockIdx.x * 4 + (threadIdx.x >> 6);
    int l = threadIdx.x & 63;
    int r = l & 15, g = l >> 4;
    const float* rp = src + (t * 16 + r) * DIM + g * 8;
    float s = 0.f;
    #pragma unroll
    for (int kc = 0; kc < 8; ++kc) {
        float4 v0 = *(const float4*)(rp + kc * 32);
        float4 v1 = *(const float4*)(rp + kc * 32 + 4);
        bf16x8 o;
        o[0] = f2bf(v0.x); o[1] = f2bf(v0.y); o[2] = f2bf(v0.z); o[3] = f2bf(v0.w);
        o[4] = f2bf(v1.x); o[5] = f2bf(v1.y); o[6] = f2bf(v1.z); o[7] = f2bf(v1.w);
        *(bf16x8*)(dst + (t * 8 + kc) * 512 + l * 8) = o;
        s += v0.x*v0.x + v0.y*v0.y + v0.z*v0.z + v0.w*v0.w
           + v1.x*v1.x + v1.y*v1.y + v1.z*v1.z + v1.w*v1.w;
    }
    s += __shfl_xor(s, 16);
    s += __shfl_xor(s, 32);
    if (g == 0) sq[t * 16 + r] = s;
}

// ---- kall: convert X + full argmax + gather + loss, one kernel --------
// grid 256 = 1 block/CU; block owns 64 X rows (4 subtiles, wave wid owns
// subtile wid). Loops 16 codebook chunks (32KB each) with LDS dbuf.
// Score = dot; index in low 10 mantissa bits; running fmaxf in regs.
__global__ __launch_bounds__(256) void kall(
        const float* __restrict__ X,
        const unsigned short* __restrict__ Ebf,
        const float* __restrict__ esq, const float* __restrict__ E,
        float* __restrict__ outq, float* __restrict__ bsum) {
    __shared__ unsigned short Eb[2][16384];   // 64 KB double buffer
    __shared__ float    sxsq[64];
    __shared__ unsigned spack[64];

    int tid  = threadIdx.x;
    int wid  = tid >> 6;
    int lane = tid & 63;
    int r15  = lane & 15;
    int g    = lane >> 4;
    int m0   = blockIdx.x * 64;

    // issue stage of chunk 0 first (overlaps with phase A)
    {
        const char* gs = (const char*)Ebf;
        char* ls = (char*)&Eb[0][0];
        #pragma unroll
        for (int i = 0; i < 8; ++i) {
            int off = i * 4096 + tid * 16;
            __builtin_amdgcn_global_load_lds(
                (const __attribute__((address_space(1))) unsigned int*)(gs + off),
                (__attribute__((address_space(3))) unsigned int*)(ls + off),
                16, 0, 0);
        }
    }

    // phase A: convert this wave's 16 X rows to A fragments (registers)
    bf16x8 a[8];
    {
        const float* rp = X + (m0 + wid * 16 + r15) * DIM + g * 8;
        float s = 0.f;
        #pragma unroll
        for (int kc = 0; kc < 8; ++kc) {
            float4 v0 = *(const float4*)(rp + kc * 32);
            float4 v1 = *(const float4*)(rp + kc * 32 + 4);
            bf16x8 o;
            o[0] = f2bf(v0.x); o[1] = f2bf(v0.y); o[2] = f2bf(v0.z); o[3] = f2bf(v0.w);
            o[4] = f2bf(v1.x); o[5] = f2bf(v1.y); o[6] = f2bf(v1.z); o[7] = f2bf(v1.w);
            a[kc] = o;
            s += v0.x*v0.x + v0.y*v0.y + v0.z*v0.z + v0.w*v0.w
               + v1.x*v1.x + v1.y*v1.y + v1.z*v1.z + v1.w*v1.w;
        }
        s += __shfl_xor(s, 16);
        s += __shfl_xor(s, 32);
        if (g == 0) sxsq[wid * 16 + r15] = s;
    }
    __syncthreads();   // chunk 0 staged, sxsq visible

    // phase B: stream 16 codebook chunks, running packed argmax
    float bv[4] = {-INFINITY, -INFINITY, -INFINITY, -INFINITY};

    for (int c = 0; c < 16; ++c) {
        if (c < 15) {
            const char* gs = (const char*)(Ebf + (c + 1) * 16384);
            char* ls = (char*)&Eb[(c + 1) & 1][0];
            #pragma unroll
            for (int i = 0; i < 8; ++i) {
                int off = i * 4096 + tid * 16;
                __builtin_amdgcn_global_load_lds(
                    (const __attribute__((address_space(1))) unsigned int*)(gs + off),
                    (__attribute__((address_space(3))) unsigned int*)(ls + off),
                    16, 0, 0);
            }
        }
        const unsigned short* bp = &Eb[c & 1][0];
        #pragma unroll
        for (int s2 = 0; s2 < 4; s2 += 2) {
            bf16x8 b0[8], b1[8];
            #pragma unroll
            for (int kc = 0; kc < 8; ++kc) {
                b0[kc] = *(const bf16x8*)(bp + (s2 + 0) * 4096 + kc * 512 + lane * 8);
                b1[kc] = *(const bf16x8*)(bp + (s2 + 1) * 4096 + kc * 512 + lane * 8);
            }
            f32x4 c0 = {0.f,0.f,0.f,0.f}, c1 = {0.f,0.f,0.f,0.f};
            #pragma unroll
            for (int kc = 0; kc < 8; ++kc) {
                c0 = __builtin_amdgcn_mfma_f32_16x16x32_bf16(a[kc], b0[kc], c0, 0, 0, 0);
                c1 = __builtin_amdgcn_mfma_f32_16x16x32_bf16(a[kc], b1[kc], c1, 0, 0, 0);
            }
            int bidx0 = c * 64 + (s2 + 0) * 16 + r15;
            int bidx1 = bidx0 + 16;
            #pragma unroll
            for (int r = 0; r < 4; ++r) {
                float f0 = __uint_as_float((__float_as_uint(c0[r]) & 0xFFFFFC00u) | bidx0);
                bv[r] = fmaxf(bv[r], f0);
                float f1 = __uint_as_float((__float_as_uint(c1[r]) & 0xFFFFFC00u) | bidx1);
                bv[r] = fmaxf(bv[r], f1);
            }
        }
        __syncthreads();   // drains stage(c+1); protects dbuf reuse
    }

    // phase C: reduce across the 16 lanes of each row-group
    #pragma unroll
    for (int m = 1; m <= 8; m <<= 1) {
        #pragma unroll
        for (int r = 0; r < 4; ++r)
            bv[r] = fmaxf(bv[r], __shfl_xor(bv[r], m));
    }
    if (r15 == 0) {
        #pragma unroll
        for (int r = 0; r < 4; ++r)
            spack[wid * 16 + g * 4 + r] = __float_as_uint(bv[r]);  // row=(l>>4)*4+reg
    }
    __syncthreads();

    // phase D1: loss partial (threads 0..63, one row each)
    if (tid < 64) {
        unsigned vb = spack[tid];
        int idx    = (int)(vb & 1023u);
        float dotc = __uint_as_float(vb & 0xFFFFFC00u);
        float l = sxsq[tid] + esq[idx] - 2.f * dotc;   // ||x-e||^2
        #pragma unroll
        for (int m = 1; m <= 32; m <<= 1) l += __shfl_xor(l, m);
        if (tid == 0) bsum[blockIdx.x] = l;
    }

    // phase D2: gather E[idx] (exact f32), one coalesced row per iter
    #pragma unroll 4
    for (int p = 0; p < 64; ++p) {
        int idx = (int)(spack[p] & 1023u);
        outq[(m0 + p) * DIM + tid] = E[idx * DIM + tid];
    }
}

// ---- k3: reduce 256 partials -> loss ----------------------------------
__global__ __launch_bounds__(256) void k3_loss(
        const float* __restrict__ bsum, float* __restrict__ out) {
    __shared__ float ls[4];
    int tid = threadIdx.x;
    float s = bsum[tid];
    #pragma unroll
    for (int m = 1; m <= 32; m <<= 1) s += __shfl_xor(s, m);
    if ((tid & 63) == 0) ls[tid >> 6] = s;
    __syncthreads();
    if (tid == 0)
        out[0] = 1.25f * (ls[0] + ls[1] + ls[2] + ls[3]) * (1.0f / NUMEL);
}

extern "C" void kernel_launch(void* const* d_in, const int* in_sizes, int n_in,
                              void* d_out, int out_size, void* d_ws, size_t ws_size,
                              hipStream_t stream) {
    const float* X = (const float*)d_in[0];   // [8,2048,256] f32
    const float* E = (const float*)d_in[1];   // [1024,256]   f32
    float* out = (float*)d_out;               // [1 + 4194304] f32
    char* ws = (char*)d_ws;

    unsigned short* Ebf = (unsigned short*)ws;
    float* esq  = (float*)(ws + 524288);
    float* bsum = (float*)(ws + 528384);

    kprepE<<<NUM_EMB / 64, 256, 0, stream>>>(E, Ebf, esq);
    kall<<<ROWS / 64, 256, 0, stream>>>(X, Ebf, esq, E, out + 1, bsum);
    k3_loss<<<1, 256, 0, stream>>>(bsum, out);
}

// Round 12
// 93.406 us; speedup vs baseline: 1.0552x; 1.0552x over previous
//
#include <hip/hip_runtime.h>
#include <math.h>

#define DIM 256
#define NUM_EMB 1024
#define ROWS 16384
#define NCH 16           // codebook chunks (64 rows / 32KB each)
#define NUMEL 4194304.0f // 8*2048*256

typedef __attribute__((ext_vector_type(8))) short bf16x8;
typedef __attribute__((ext_vector_type(4))) float f32x4;

// f32 -> bf16 round-to-nearest-even (bit pattern)
__device__ __forceinline__ unsigned short f2bf(float f) {
    unsigned int u = __float_as_uint(f);
    u = (u + 0x7FFFu + ((u >> 16) & 1u)) >> 16;
    return (unsigned short)u;
}

// ws layout (bytes):
//   Ebf : [0,       524288)   bf16 codebook, fragment-linear:
//         subtile t=row/16, kc=dim/32 -> 1024B block; lane l=16g+r holds
//         row t*16+r, dims [kc*32+8g,+8) at ushort off (t*8+kc)*512 + l*8
//   Xbf : [524288,  8912896)  bf16 inputs, same layout (1024 subtiles)
//   esq : [8912896, 8916992)  f32 [1024]  exact codebook row norms
//   xsq : [8916992, 8982528)  f32 [16384] exact input row norms
//   pval: [8982528,10031104)  f32 [16384][16] packed (dot | idx) per chunk
//   bsum: [10031104,10047488) f32 [4096] per-block loss partials

// ---- kprep: f32 rows -> fragment-linear bf16 + exact row sq-norms -----
// blocks 0..15 -> codebook, blocks 16..271 -> inputs (one launch).
__global__ __launch_bounds__(256) void kprep(
        const float* __restrict__ E, const float* __restrict__ X,
        unsigned short* __restrict__ Ebf, unsigned short* __restrict__ Xbf,
        float* __restrict__ esq, float* __restrict__ xsq) {
    bool isE = blockIdx.x < 16;
    const float* src        = isE ? E   : X;
    unsigned short* dst     = isE ? Ebf : Xbf;
    float* sq               = isE ? esq : xsq;
    int bb                  = isE ? blockIdx.x : blockIdx.x - 16;

    int t = bb * 4 + (threadIdx.x >> 6);
    int l = threadIdx.x & 63;
    int r = l & 15, g = l >> 4;
    const float* rp = src + (t * 16 + r) * DIM + g * 8;
    float s = 0.f;
    #pragma unroll
    for (int kc = 0; kc < 8; ++kc) {
        float4 v0 = *(const float4*)(rp + kc * 32);
        float4 v1 = *(const float4*)(rp + kc * 32 + 4);
        bf16x8 o;
        o[0] = f2bf(v0.x); o[1] = f2bf(v0.y); o[2] = f2bf(v0.z); o[3] = f2bf(v0.w);
        o[4] = f2bf(v1.x); o[5] = f2bf(v1.y); o[6] = f2bf(v1.z); o[7] = f2bf(v1.w);
        *(bf16x8*)(dst + (t * 8 + kc) * 512 + l * 8) = o;
        s += v0.x*v0.x + v0.y*v0.y + v0.z*v0.z + v0.w*v0.w
           + v1.x*v1.x + v1.y*v1.y + v1.z*v1.z + v1.w*v1.w;
    }
    s += __shfl_xor(s, 16);
    s += __shfl_xor(s, 32);
    if (g == 0) sq[t * 16 + r] = s;
}

// ---- kmain: packed-argmax of dot over one 64-row codebook chunk -------
// grid 2048 = 128 mgroups (fast) x 16 chunks. 4 waves; wave owns 2
// M-subtiles (32 rows); chunk (4 subtiles, 32KB) staged in LDS.
// Score = dot(x,e); index packed into low 10 mantissa bits -> v_max only.
__global__ __launch_bounds__(256) void kmain(
        const unsigned short* __restrict__ Xbf,
        const unsigned short* __restrict__ Ebf,
        float* __restrict__ pval) {
    __shared__ unsigned short Eb[16384];   // 32 KB

    int tid  = threadIdx.x;
    int wid  = tid >> 6;
    int lane = tid & 63;
    int r15  = lane & 15;
    int g    = lane >> 4;
    int mg    = blockIdx.x & 127;          // same-mg blocks -> same XCD
    int chunk = blockIdx.x >> 7;

    // async stage: 32KB codebook chunk -> LDS (linear)
    {
        const char* gs = (const char*)(Ebf + chunk * 16384);
        char* ls = (char*)Eb;
        #pragma unroll
        for (int i = 0; i < 8; ++i) {
            int off = i * 4096 + tid * 16;
            __builtin_amdgcn_global_load_lds(
                (const __attribute__((address_space(1))) unsigned int*)(gs + off),
                (__attribute__((address_space(3))) unsigned int*)(ls + off),
                16, 0, 0);
        }
    }

    // A fragments (overlaps staging): 2 subtiles = 32 rows
    int t0 = mg * 8 + wid * 2;
    bf16x8 a0[8], a1[8];
    #pragma unroll
    for (int kc = 0; kc < 8; ++kc) {
        a0[kc] = *(const bf16x8*)(Xbf + ((t0 + 0) * 8 + kc) * 512 + lane * 8);
        a1[kc] = *(const bf16x8*)(Xbf + ((t0 + 1) * 8 + kc) * 512 + lane * 8);
    }
    __syncthreads();   // drains vmcnt (staging + A loads)

    float bv0[4] = {-INFINITY,-INFINITY,-INFINITY,-INFINITY};
    float bv1[4] = {-INFINITY,-INFINITY,-INFINITY,-INFINITY};

    #pragma unroll
    for (int s = 0; s < 4; ++s) {
        bf16x8 b[8];
        #pragma unroll
        for (int kc = 0; kc < 8; ++kc)
            b[kc] = *(const bf16x8*)(Eb + s * 4096 + kc * 512 + lane * 8);
        f32x4 c0 = {0.f,0.f,0.f,0.f}, c1 = {0.f,0.f,0.f,0.f};
        #pragma unroll
        for (int kc = 0; kc < 8; ++kc) {
            c0 = __builtin_amdgcn_mfma_f32_16x16x32_bf16(a0[kc], b[kc], c0, 0, 0, 0);
            c1 = __builtin_amdgcn_mfma_f32_16x16x32_bf16(a1[kc], b[kc], c1, 0, 0, 0);
        }
        int bidx = chunk * 64 + s * 16 + r15;   // codebook row, 10 bits
        #pragma unroll
        for (int r = 0; r < 4; ++r) {
            float f0 = __uint_as_float((__float_as_uint(c0[r]) & 0xFFFFFC00u) | bidx);
            bv0[r] = fmaxf(bv0[r], f0);
            float f1 = __uint_as_float((__float_as_uint(c1[r]) & 0xFFFFFC00u) | bidx);
            bv1[r] = fmaxf(bv1[r], f1);
        }
    }

    // max across the 16 lanes of each row-group (index rides along)
    #pragma unroll
    for (int m = 1; m <= 8; m <<= 1) {
        #pragma unroll
        for (int r = 0; r < 4; ++r) {
            bv0[r] = fmaxf(bv0[r], __shfl_xor(bv0[r], m));
            bv1[r] = fmaxf(bv1[r], __shfl_xor(bv1[r], m));
        }
    }
    if (r15 == 0) {
        #pragma unroll
        for (int r = 0; r < 4; ++r) {
            int row0 = mg * 128 + wid * 32 + g * 4 + r;  // C/D: row=(l>>4)*4+reg
            int row1 = row0 + 16;
            pval[row0 * NCH + chunk] = bv0[r];
            pval[row1 * NCH + chunk] = bv1[r];
        }
    }
}

// ---- kfinal: merge chunks, gather E[idx], loss from norms+dot ---------
__global__ __launch_bounds__(256) void kfinal(
        const float* __restrict__ pval, const float* __restrict__ xsq,
        const float* __restrict__ esq, const float* __restrict__ E,
        float* __restrict__ outq, float* __restrict__ bsum) {
    __shared__ float ls[4];
    int tid  = threadIdx.x;
    int wid  = tid >> 6;
    int lane = tid & 63;
    int row  = blockIdx.x * 4 + wid;

    float v = pval[row * NCH + (lane & 15)];   // replicated across 4 groups
    #pragma unroll
    for (int m = 1; m <= 8; m <<= 1) v = fmaxf(v, __shfl_xor(v, m));
    unsigned vb = __float_as_uint(v);
    int idx    = (int)(vb & 1023u);
    float dotc = __uint_as_float(vb & 0xFFFFFC00u);  // clipped bf16-dot

    #pragma unroll
    for (int j = 0; j < 4; ++j)
        outq[row * DIM + j * 64 + lane] = E[idx * DIM + j * 64 + lane];

    if (lane == 0) ls[wid] = xsq[row] + esq[idx] - 2.f * dotc;  // ||x-e||^2
    __syncthreads();
    if (tid == 0) bsum[blockIdx.x] = ls[0] + ls[1] + ls[2] + ls[3];
}

// ---- k3: reduce 4096 partials -> loss ---------------------------------
__global__ __launch_bounds__(1024) void k3_loss(
        const float* __restrict__ bsum, float* __restrict__ out) {
    __shared__ float ls[16];
    int t = threadIdx.x;
    float s = bsum[t] + bsum[t + 1024] + bsum[t + 2048] + bsum[t + 3072];
    #pragma unroll
    for (int m = 1; m <= 32; m <<= 1) s += __shfl_xor(s, m);
    int wid = t >> 6, lane = t & 63;
    if (lane == 0) ls[wid] = s;
    __syncthreads();
    if (wid == 0) {
        float v = (lane < 16) ? ls[lane] : 0.f;
        #pragma unroll
        for (int m = 1; m <= 8; m <<= 1) v += __shfl_xor(v, m);
        if (lane == 0) out[0] = 1.25f * v * (1.0f / NUMEL);
    }
}

extern "C" void kernel_launch(void* const* d_in, const int* in_sizes, int n_in,
                              void* d_out, int out_size, void* d_ws, size_t ws_size,
                              hipStream_t stream) {
    const float* X = (const float*)d_in[0];   // [8,2048,256] f32
    const float* E = (const float*)d_in[1];   // [1024,256]   f32
    float* out = (float*)d_out;               // [1 + 4194304] f32
    char* ws = (char*)d_ws;

    unsigned short* Ebf = (unsigned short*)ws;
    unsigned short* Xbf = (unsigned short*)(ws + 524288);
    float* esq  = (float*)(ws + 8912896);
    float* xsq  = (float*)(ws + 8916992);
    float* pval = (float*)(ws + 8982528);
    float* bsum = (float*)(ws + 10031104);

    kprep<<<16 + ROWS / 64, 256, 0, stream>>>(E, X, Ebf, Xbf, esq, xsq);
    kmain<<<128 * NCH, 256, 0, stream>>>(Xbf, Ebf, pval);
    kfinal<<<ROWS / 4, 256, 0, stream>>>(pval, xsq, esq, E, out + 1, bsum);
    k3_loss<<<1, 1024, 0, stream>>>(bsum, out);
}